// Round 1
// baseline (106.740 us; speedup 1.0000x reference)
//
#include <hip/hip_runtime.h>

// VQC: 8 qubits, RY(x_i) encoding, 2 layers of [CNOT chain + RX(w_li)], <Z_i> outputs.
// One sample per 64-lane wave. Lane bit (5-i) = wire i (i=0..5); local slot j:
// bit1 = wire 6, bit0 = wire 7. Each lane holds 4 complex amplitudes.
// CNOT chain == prefix-XOR permutation; inverse is Gray code: src_lane = l ^ (l>>1).

constexpr int NQ = 8;

__global__ __launch_bounds__(256) void vqc_kernel(
    const float* __restrict__ inputs,   // (B, 8) f32
    const float* __restrict__ weights,  // (2, 8) f32
    float* __restrict__ out,            // (B, 8) f32
    int B)
{
    const int lane   = threadIdx.x & 63;
    const int wave   = threadIdx.x >> 6;
    const int sample = (blockIdx.x << 2) + wave;
    if (sample >= B) return;

    // ---- per-sample encoding angles (wave-broadcast load, 32B) ----
    const float4* row = reinterpret_cast<const float4*>(inputs + sample * NQ);
    const float4 a4 = row[0], b4 = row[1];
    const float x[NQ] = {a4.x, a4.y, a4.z, a4.w, b4.x, b4.y, b4.z, b4.w};

    float ec[NQ], es[NQ];
#pragma unroll
    for (int i = 0; i < NQ; ++i) {
        ec[i] = __cosf(0.5f * x[i]);
        es[i] = __sinf(0.5f * x[i]);
    }

    // ---- shared RX angles ----
    float wc[2][NQ], ws[2][NQ];
#pragma unroll
    for (int l = 0; l < 2; ++l)
#pragma unroll
        for (int i = 0; i < NQ; ++i) {
            float h = 0.5f * weights[l * NQ + i];
            wc[l][i] = __cosf(h);
            ws[l][i] = __sinf(h);
        }

    // ---- RY-encoded product state, built directly ----
    float F = 1.0f;
#pragma unroll
    for (int i = 0; i < 6; ++i)
        F *= ((lane >> (5 - i)) & 1) ? es[i] : ec[i];

    float re[4], im[4];
    re[0] = F * ec[6] * ec[7];
    re[1] = F * ec[6] * es[7];
    re[2] = F * es[6] * ec[7];
    re[3] = F * es[6] * es[7];
#pragma unroll
    for (int j = 0; j < 4; ++j) im[j] = 0.0f;

    const int tp = __popc(lane) & 1;    // parity(my lane) == low bit of my pull-target
    const int sl = lane ^ (lane >> 1);  // Gray code: the lane I pull from

#pragma unroll
    for (int layer = 0; layer < 2; ++layer) {
        // ---- full CNOT chain as ONE permutation ----
        // new[m] = old[b], b_0=m_0, b_i=m_{i-1}^m_i. Cross-lane part: src = gray(lane).
        // Local slots the source must serve (depend on target parity tp):
        //   tp=0: [0,1,3,2]   tp=1: [2,3,1,0]
        float sre[4], sim[4];
        sre[0] = tp ? re[2] : re[0];  sim[0] = tp ? im[2] : im[0];
        sre[1] = tp ? re[3] : re[1];  sim[1] = tp ? im[3] : im[1];
        sre[2] = tp ? re[1] : re[3];  sim[2] = tp ? im[1] : im[3];
        sre[3] = tp ? re[0] : re[2];  sim[3] = tp ? im[0] : im[2];
#pragma unroll
        for (int j = 0; j < 4; ++j) {
            re[j] = __shfl(sre[j], sl, 64);
            im[j] = __shfl(sim[j], sl, 64);
        }

        // ---- RX on wires 0..5 (cross-lane; RX is symmetric: v' = c*v - i*s*other) ----
#pragma unroll
        for (int w = 0; w < 6; ++w) {
            const float c = wc[layer][w], s = ws[layer][w];
            const int mask = 1 << (5 - w);
#pragma unroll
            for (int j = 0; j < 4; ++j) {
                const float orr = __shfl_xor(re[j], mask, 64);
                const float oii = __shfl_xor(im[j], mask, 64);
                const float nr = __builtin_fmaf(s, oii, c * re[j]);
                const float ni = __builtin_fmaf(-s, orr, c * im[j]);
                re[j] = nr; im[j] = ni;
            }
        }
        // ---- RX wire 6: local pairs (0,2),(1,3) ----
        {
            const float c = wc[layer][6], s = ws[layer][6];
            const float nr0 = __builtin_fmaf(s, im[2], c * re[0]);
            const float ni0 = __builtin_fmaf(-s, re[2], c * im[0]);
            const float nr2 = __builtin_fmaf(s, im[0], c * re[2]);
            const float ni2 = __builtin_fmaf(-s, re[0], c * im[2]);
            const float nr1 = __builtin_fmaf(s, im[3], c * re[1]);
            const float ni1 = __builtin_fmaf(-s, re[3], c * im[1]);
            const float nr3 = __builtin_fmaf(s, im[1], c * re[3]);
            const float ni3 = __builtin_fmaf(-s, re[1], c * im[3]);
            re[0]=nr0; im[0]=ni0; re[1]=nr1; im[1]=ni1;
            re[2]=nr2; im[2]=ni2; re[3]=nr3; im[3]=ni3;
        }
        // ---- RX wire 7: local pairs (0,1),(2,3) ----
        {
            const float c = wc[layer][7], s = ws[layer][7];
            const float nr0 = __builtin_fmaf(s, im[1], c * re[0]);
            const float ni0 = __builtin_fmaf(-s, re[1], c * im[0]);
            const float nr1 = __builtin_fmaf(s, im[0], c * re[1]);
            const float ni1 = __builtin_fmaf(-s, re[0], c * im[1]);
            const float nr2 = __builtin_fmaf(s, im[3], c * re[2]);
            const float ni2 = __builtin_fmaf(-s, re[3], c * im[2]);
            const float nr3 = __builtin_fmaf(s, im[2], c * re[3]);
            const float ni3 = __builtin_fmaf(-s, re[2], c * im[3]);
            re[0]=nr0; im[0]=ni0; re[1]=nr1; im[1]=ni1;
            re[2]=nr2; im[2]=ni2; re[3]=nr3; im[3]=ni3;
        }
    }

    // ---- measurement: <Z_i> = sum_n |amp_n|^2 * (-1)^{bit_i(n)} ----
    float p[4];
#pragma unroll
    for (int j = 0; j < 4; ++j) p[j] = re[j]*re[j] + im[j]*im[j];
    const float ptot = (p[0] + p[1]) + (p[2] + p[3]);

    float z[8];
#pragma unroll
    for (int i = 0; i < 6; ++i)
        z[i] = ((lane >> (5 - i)) & 1) ? -ptot : ptot;
    z[6] = (p[0] + p[1]) - (p[2] + p[3]);   // wire 6 = slot bit1
    z[7] = (p[0] - p[1]) + (p[2] - p[3]);   // wire 7 = slot bit0

#pragma unroll
    for (int m = 1; m < 64; m <<= 1) {
#pragma unroll
        for (int i = 0; i < 8; ++i)
            z[i] += __shfl_xor(z[i], m, 64);
    }

    if (lane == 0) {
        float4* o = reinterpret_cast<float4*>(out + sample * NQ);
        o[0] = make_float4(z[0], z[1], z[2], z[3]);
        o[1] = make_float4(z[4], z[5], z[6], z[7]);
    }
}

extern "C" void kernel_launch(void* const* d_in, const int* in_sizes, int n_in,
                              void* d_out, int out_size, void* d_ws, size_t ws_size,
                              hipStream_t stream) {
    const float* inputs  = (const float*)d_in[0];
    const float* weights = (const float*)d_in[1];
    float* out = (float*)d_out;
    const int B = in_sizes[0] / NQ;          // 65536
    const int blocks = (B + 3) / 4;          // 4 waves (samples) per 256-thread block
    vqc_kernel<<<blocks, 256, 0, stream>>>(inputs, weights, out, B);
}

// Round 3
// 38.125 us; speedup vs baseline: 2.7997x; 2.7997x over previous
//
#include <hip/hip_runtime.h>

// VQC 8 qubits: RY(x) encoding, 2x [CNOT chain + RX(w)], <Z_i>.
// Lazy-CNOT: chain = GF(2) linear map P (prefix-xor). Keep amplitudes in
// place, track A = P^layer. RX on wire w then pairs PHYSICAL indices with
// XOR mask = col_w(A^-1):  layer0: e_w^e_{w+1},  layer1: e_w^e_{w+2}.
// Measurement sign for <Z_w> = parity(p & row_w(P^2)), R_w = {w,w-2,...}.
//
// Layout: 8 lanes/sample (wires 0,1,2 -> lane bits 0,1,2),
//         32 amps/lane  (wires 3..7  -> slot bits 0..4).
// 10/16 gates local (pure VALU), 2 via DPP quad_perm (VALU), 4 via ds_swizzle.

constexpr int NQ = 8;

template<int CTRL>
__device__ __forceinline__ float dpp_qp(float v) {
    return __builtin_bit_cast(float,
        __builtin_amdgcn_mov_dpp(__builtin_bit_cast(int, v), CTRL, 0xf, 0xf, true));
}

// lane-xor within the 8-lane group. 1,2,3 -> DPP quad_perm (VALU pipe);
// 4,5,6 -> ds_swizzle BitMode xor (LDS pipe).
template<int M>
__device__ __forceinline__ float lxor(float v) {
    if constexpr (M == 1)      return dpp_qp<0xB1>(v);   // [1,0,3,2]
    else if constexpr (M == 2) return dpp_qp<0x4E>(v);   // [2,3,0,1]
    else if constexpr (M == 3) return dpp_qp<0x1B>(v);   // [3,2,1,0]
    else return __builtin_bit_cast(float,
        __builtin_amdgcn_ds_swizzle(__builtin_bit_cast(int, v), (M << 10) | 0x1f));
}

// RX update: v' = c*v - i*s*v_partner  (symmetric, no bit-order dependence)

// local gate: slot-xor mask ML (HB = highest bit of ML selects one rep per pair)
template<int ML, int HB>
__device__ __forceinline__ void gate_local(float (&re)[32], float (&im)[32],
                                           float c, float s) {
#pragma unroll
    for (int p = 0; p < 32; ++p) {
        if ((p & HB) == 0) {
            const int q = p ^ ML;
            const float r0 = re[p], i0 = im[p], r1 = re[q], i1 = im[q];
            re[p] = __builtin_fmaf(s, i1, c * r0);
            im[p] = __builtin_fmaf(-s, r1, c * i0);
            re[q] = __builtin_fmaf(s, i0, c * r1);
            im[q] = __builtin_fmaf(-s, r0, c * i1);
        }
    }
}

// cross gate: lane-xor LX, slot-xor ML (0, or single-bit with HB=ML)
template<int LX, int ML, int HB>
__device__ __forceinline__ void gate_cross(float (&re)[32], float (&im)[32],
                                           float c, float s) {
    if constexpr (ML == 0) {
#pragma unroll
        for (int p = 0; p < 32; ++p) {
            const float pr = lxor<LX>(re[p]);
            const float pi = lxor<LX>(im[p]);
            re[p] = __builtin_fmaf(s, pi, c * re[p]);
            im[p] = __builtin_fmaf(-s, pr, c * im[p]);
        }
    } else {
#pragma unroll
        for (int p = 0; p < 32; ++p) {
            if ((p & HB) == 0) {
                const int q = p ^ ML;
                const float r0 = re[p], i0 = im[p], r1 = re[q], i1 = im[q];
                const float pr0 = lxor<LX>(r1), pi0 = lxor<LX>(i1); // partner (lane^LX, q)
                const float pr1 = lxor<LX>(r0), pi1 = lxor<LX>(i0); // partner (lane^LX, p)
                re[p] = __builtin_fmaf(s, pi0, c * r0);
                im[p] = __builtin_fmaf(-s, pr0, c * i0);
                re[q] = __builtin_fmaf(s, pi1, c * r1);
                im[q] = __builtin_fmaf(-s, pr1, c * i1);
            }
        }
    }
}

// first gate of layer 0: state is purely real -> half the work, writes all im
template<int LX>
__device__ __forceinline__ void gate_cross_real(float (&re)[32], float (&im)[32],
                                                float c, float s) {
#pragma unroll
    for (int p = 0; p < 32; ++p) {
        const float pr = lxor<LX>(re[p]);
        im[p] = -s * pr;
        re[p] = c * re[p];
    }
}

__global__ __launch_bounds__(256) void vqc_kernel(
    const float* __restrict__ inputs,   // (B, 8) f32
    const float* __restrict__ weights,  // (2, 8) f32
    float* __restrict__ out,            // (B, 8) f32
    int B)
{
    const int tid    = blockIdx.x * 256 + threadIdx.x;
    const int sample = tid >> 3;
    const int ll     = threadIdx.x & 7;      // lane within 8-lane sample group
    if (sample >= B) return;

    // ---- load this sample's angles (8 lanes share 32B; L1 broadcast) ----
    const float4* rowp = reinterpret_cast<const float4*>(inputs + (size_t)sample * NQ);
    const float4 A4 = rowp[0], B4 = rowp[1];
    const float x[NQ] = {A4.x, A4.y, A4.z, A4.w, B4.x, B4.y, B4.z, B4.w};
    float ec[NQ], es[NQ];
#pragma unroll
    for (int j = 0; j < NQ; ++j) __sincosf(0.5f * x[j], &es[j], &ec[j]);

    // ---- RY product state (real), wires 0-2 from lane, 3-7 from slot ----
    const float b0 = (ll & 1) ? es[0] : ec[0];
    const float b1 = (ll & 2) ? es[1] : ec[1];
    const float b2 = (ll & 4) ? es[2] : ec[2];
    float re[32], im[32];
    re[0] = b0 * b1 * b2;
#pragma unroll
    for (int k = 0; k < 5; ++k) {
        const int n = 1 << k;
#pragma unroll
        for (int t = 0; t < n; ++t) {
            re[t + n] = re[t] * es[3 + k];
            re[t]     = re[t] * ec[3 + k];
        }
    }
    // im[] is written by the first (real-input) gate below.

    // ---- Layer 0: masks e_w ^ e_{w+1} (w7: e7) ----
    {
        float c[NQ], s[NQ];
#pragma unroll
        for (int j = 0; j < NQ; ++j) __sincosf(0.5f * weights[j], &s[j], &c[j]);
        gate_cross_real<3>(re, im, c[0], s[0]);     // wires{0,1}: lane xor3 (DPP)
        gate_cross<6, 0, 0>(re, im, c[1], s[1]);    // wires{1,2}: lane xor6
        gate_cross<4, 1, 1>(re, im, c[2], s[2]);    // wires{2,3}: lane4 + slot1
        gate_local<3, 2>(re, im, c[3], s[3]);       // wires{3,4}: slot 0^1
        gate_local<6, 4>(re, im, c[4], s[4]);       // wires{4,5}
        gate_local<12, 8>(re, im, c[5], s[5]);      // wires{5,6}
        gate_local<24, 16>(re, im, c[6], s[6]);     // wires{6,7}
        gate_local<16, 16>(re, im, c[7], s[7]);     // wire{7}
    }
    // ---- Layer 1: masks e_w ^ e_{w+2} (w6: e6, w7: e7) ----
    {
        float c[NQ], s[NQ];
#pragma unroll
        for (int j = 0; j < NQ; ++j) __sincosf(0.5f * weights[NQ + j], &s[j], &c[j]);
        gate_cross<5, 0, 0>(re, im, c[0], s[0]);    // wires{0,2}: lane xor5
        gate_cross<2, 1, 1>(re, im, c[1], s[1]);    // wires{1,3}: lane2 (DPP) + slot1
        gate_cross<4, 2, 2>(re, im, c[2], s[2]);    // wires{2,4}: lane4 + slot2
        gate_local<5, 4>(re, im, c[3], s[3]);       // wires{3,5}
        gate_local<10, 8>(re, im, c[4], s[4]);      // wires{4,6}
        gate_local<20, 16>(re, im, c[5], s[5]);     // wires{5,7}
        gate_local<8, 8>(re, im, c[6], s[6]);       // wire{6}
        gate_local<16, 16>(re, im, c[7], s[7]);     // wire{7}
    }

    // ---- measurement: signed sums over slots, masks = slot part of R_w ----
    float T0 = 0, T1 = 0, T2 = 0, T5 = 0, T10 = 0, T21 = 0;
#pragma unroll
    for (int p = 0; p < 32; ++p) {
        const float pw = __builtin_fmaf(re[p], re[p], im[p] * im[p]);
        T0 += pw;
        if (__builtin_popcount(p & 1)  & 1) T1  -= pw; else T1  += pw;
        if (__builtin_popcount(p & 2)  & 1) T2  -= pw; else T2  += pw;
        if (__builtin_popcount(p & 5)  & 1) T5  -= pw; else T5  += pw;
        if (__builtin_popcount(p & 10) & 1) T10 -= pw; else T10 += pw;
        if (__builtin_popcount(p & 21) & 1) T21 -= pw; else T21 += pw;
    }
    // lane-sign part of R_w (R_w = {w, w-2, ...}; lane bits are wires 0,1,2)
    const float s1 = (ll & 1) ? -1.f : 1.f;
    const float s2 = (ll & 2) ? -1.f : 1.f;
    const float s4 = (ll & 4) ? -1.f : 1.f;
    const float s5 = s1 * s4;
    // R_0={0}:s1  R_1={1}:s2  R_2={2,0}:s5  R_3={3,1}:s2
    // R_4={4,2,0}:s5  R_5={5,3,1}:s2  R_6={6,4,2,0}:s5  R_7={7,5,3,1}:s2
    float z[8] = { s1 * T0,  s2 * T0,  s5 * T0,  s2 * T1,
                   s5 * T2,  s2 * T5,  s5 * T10, s2 * T21 };

    // reduce over the 8-lane group
#pragma unroll
    for (int i = 0; i < 8; ++i) {
        float v = z[i];
        v += lxor<1>(v);
        v += lxor<2>(v);
        v += lxor<4>(v);
        z[i] = v;
    }

    if (ll == 0) {
        float4* o = reinterpret_cast<float4*>(out + (size_t)sample * NQ);
        o[0] = make_float4(z[0], z[1], z[2], z[3]);
        o[1] = make_float4(z[4], z[5], z[6], z[7]);
    }
}

extern "C" void kernel_launch(void* const* d_in, const int* in_sizes, int n_in,
                              void* d_out, int out_size, void* d_ws, size_t ws_size,
                              hipStream_t stream) {
    const float* inputs  = (const float*)d_in[0];
    const float* weights = (const float*)d_in[1];
    float* out = (float*)d_out;
    const int B = in_sizes[0] / NQ;               // 65536
    const int total = B * 8;                      // 8 lanes per sample
    const int blocks = (total + 255) / 256;       // 2048
    vqc_kernel<<<blocks, 256, 0, stream>>>(inputs, weights, out, B);
}

// Round 4
// 28.342 us; speedup vs baseline: 3.7662x; 1.3452x over previous
//
#include <hip/hip_runtime.h>

// VQC 8 qubits: RY(x) encode, 2x [CNOT chain + RX(w)], <Z_i>.
// All 16 effective gates are commuting X-string rotations (CNOT chains folded
// as GF(2) relabelings): layer0 masks e_w^e_{w+1} (w7: e7), layer1 masks
// e_w^e_{w+2} (w6: e6, w7: e7). Measurement rows R_w = {w, w-2, ...}.
//
// Layout: 4 lanes/sample (wires 0,1 -> lane bits 0,1 => all cross gates are
// quad_perm DPP, zero LDS), 64 complex amps/lane (wires 2..7 -> slot bits
// 0..5). Amp = float2 (re,im) in a VGPR pair; gates use packed-fp32 VOP3P
// (v_pk_mul_f32 + v_pk_fma_f32 = 2 inst/amp).

constexpr int NQ = 8;
typedef float v2 __attribute__((ext_vector_type(2)));

template<int CTRL>
__device__ __forceinline__ float dpp_qp(float v) {
    return __builtin_bit_cast(float,
        __builtin_amdgcn_mov_dpp(__builtin_bit_cast(int, v), CTRL, 0xf, 0xf, true));
}
// lane-xor within the quad: 1 -> [1,0,3,2]=0xB1, 2 -> [2,3,0,1]=0x4E
template<int LX>
__device__ __forceinline__ float lx(float v) {
    if constexpr (LX == 1) return dpp_qp<0xB1>(v);
    else                   return dpp_qp<0x4E>(v);
}

// G = (c, s).  T = (s*U.y, -s*U.x)   [the "-i*s*U" term of RX]
__device__ __forceinline__ v2 pk_rot(v2 G, v2 U) {
    v2 d;
    asm("v_pk_mul_f32 %0, %1, %2 op_sel:[1,1] op_sel_hi:[1,0] neg_hi:[1,0]"
        : "=v"(d) : "v"(G), "v"(U));
    return d;
}
// D = (c*V.x + T.x, c*V.y + T.y)
__device__ __forceinline__ v2 pk_cfma(v2 G, v2 V, v2 T) {
    v2 d;
    asm("v_pk_fma_f32 %0, %1, %2, %3 op_sel:[0,0,0] op_sel_hi:[0,1,1]"
        : "=v"(d) : "v"(G), "v"(V), "v"(T));
    return d;
}
// V * G.x (HI=0)  or  V * G.y (HI=1), broadcast scalar from the pair
template<int HI>
__device__ __forceinline__ v2 pk_mulb(v2 V, v2 G) {
    v2 d;
    if constexpr (HI)
        asm("v_pk_mul_f32 %0, %1, %2 op_sel:[0,1] op_sel_hi:[1,1]"
            : "=v"(d) : "v"(V), "v"(G));
    else
        asm("v_pk_mul_f32 %0, %1, %2 op_sel:[0,0] op_sel_hi:[1,0]"
            : "=v"(d) : "v"(V), "v"(G));
    return d;
}

// local RX: slot-xor ML, HB = highest bit of ML (one rep per pair)
template<int ML, int HB>
__device__ __forceinline__ void gate_local(v2 (&v)[64], v2 G) {
#pragma unroll
    for (int p = 0; p < 64; ++p) if ((p & HB) == 0) {
        const int q = p ^ ML;
        v2 tp = pk_rot(G, v[q]);
        v2 tq = pk_rot(G, v[p]);
        v[p] = pk_cfma(G, v[p], tp);
        v[q] = pk_cfma(G, v[q], tq);
    }
}

// cross RX: lane-xor LX (quad DPP), slot-xor ML (1 or 2)
template<int LX, int ML>
__device__ __forceinline__ void gate_dpp(v2 (&v)[64], v2 G) {
#pragma unroll
    for (int p = 0; p < 64; ++p) if ((p & ML) == 0) {
        const int q = p ^ ML;
        v2 up, uq;
        up.x = lx<LX>(v[q].x);  up.y = lx<LX>(v[q].y);
        uq.x = lx<LX>(v[p].x);  uq.y = lx<LX>(v[p].y);
        v2 tp = pk_rot(G, up);
        v2 tq = pk_rot(G, uq);
        v[p] = pk_cfma(G, v[p], tp);
        v[q] = pk_cfma(G, v[q], tq);
    }
}

__global__ __launch_bounds__(256, 2) void vqc_kernel(
    const float* __restrict__ inputs,   // (B, 8) f32
    const float* __restrict__ weights,  // (2, 8) f32
    float* __restrict__ out,            // (B, 8) f32
    int B)
{
    const int tid    = blockIdx.x * 256 + threadIdx.x;
    const int sample = tid >> 2;
    const int ll     = threadIdx.x & 3;     // lane within the sample quad
    if (sample >= B) return;

    // ---- encoding trig: E[j] = (cos(x_j/2), sin(x_j/2)) ----
    const float4* rowp = reinterpret_cast<const float4*>(inputs + (size_t)sample * NQ);
    const float4 A4 = rowp[0], B4 = rowp[1];
    const float x[NQ] = {A4.x, A4.y, A4.z, A4.w, B4.x, B4.y, B4.z, B4.w};
    v2 E[NQ];
#pragma unroll
    for (int j = 0; j < NQ; ++j) {
        float ss, cc; __sincosf(0.5f * x[j], &ss, &cc);
        E[j].x = cc; E[j].y = ss;
    }
    // ---- layer-0 gate trig: G0[j] = (cos(w_j/2), sin(w_j/2)) ----
    v2 G0[NQ];
#pragma unroll
    for (int j = 0; j < NQ; ++j) {
        float ss, cc; __sincosf(0.5f * weights[j], &ss, &cc);
        G0[j].x = cc; G0[j].y = ss;
    }

    // ---- init product state with layer-0 gate {0,1} (lane mask 3) FOLDED ----
    // re = c0*b0*b1*slot(p),  im = -s0*b0x*b1x*slot(p)
    const float b0  = (ll & 1) ? E[0].y : E[0].x;
    const float b1  = (ll & 2) ? E[1].y : E[1].x;
    const float b0x = (ll & 1) ? E[0].x : E[0].y;
    const float b1x = (ll & 2) ? E[1].x : E[1].y;
    v2 v[64];
    v[0].x =  G0[0].x * (b0 * b1);
    v[0].y = -G0[0].y * (b0x * b1x);
#pragma unroll
    for (int k = 0; k < 6; ++k) {
        const int n = 1 << k;
#pragma unroll
        for (int t = 0; t < n; ++t) {
            v[t + n] = pk_mulb<1>(v[t], E[2 + k]);   // * sin
            v[t]     = pk_mulb<0>(v[t], E[2 + k]);   // * cos
        }
    }

    // ---- layer 0 (w=0 folded above); slot bit = wire-2 ----
    gate_dpp<2, 1>(v, G0[1]);        // {1,2}: lane^2, slot^1
    gate_local<3, 2>(v, G0[2]);      // {2,3}
    gate_local<6, 4>(v, G0[3]);      // {3,4}
    gate_local<12, 8>(v, G0[4]);     // {4,5}
    gate_local<24, 16>(v, G0[5]);    // {5,6}
    gate_local<48, 32>(v, G0[6]);    // {6,7}
    gate_local<32, 32>(v, G0[7]);    // {7}

    // ---- layer 1 ----
    v2 G1[NQ];
#pragma unroll
    for (int j = 0; j < NQ; ++j) {
        float ss, cc; __sincosf(0.5f * weights[NQ + j], &ss, &cc);
        G1[j].x = cc; G1[j].y = ss;
    }
    gate_dpp<1, 1>(v, G1[0]);        // {0,2}: lane^1, slot^1
    gate_dpp<2, 2>(v, G1[1]);        // {1,3}: lane^2, slot^2
    gate_local<5, 4>(v, G1[2]);      // {2,4}
    gate_local<10, 8>(v, G1[3]);     // {3,5}
    gate_local<20, 16>(v, G1[4]);    // {4,6}
    gate_local<40, 32>(v, G1[5]);    // {5,7}
    gate_local<16, 16>(v, G1[6]);    // {6}
    gate_local<32, 32>(v, G1[7]);    // {7}

    // ---- partial Walsh sums of pw[p]=|amp|^2 over slot masks
    //      {0,1,2,5,10,21,42} (bit b = wire b+2) ----
    float P0[32], M0[32];
#pragma unroll
    for (int e = 0; e < 32; ++e) {
        v2 ta = v[2*e]   * v[2*e];
        v2 tb = v[2*e+1] * v[2*e+1];
        const float a = ta.x + ta.y, b = tb.x + tb.y;
        P0[e] = a + b;  M0[e] = a - b;
    }
    float PP[16], PM[16], MP[16];
#pragma unroll
    for (int t = 0; t < 16; ++t) {
        PP[t] = P0[2*t] + P0[2*t+1];
        PM[t] = P0[2*t] - P0[2*t+1];
        MP[t] = M0[2*t] + M0[2*t+1];
    }
    float A0[8], A2[8], A1[8], A5[8];
#pragma unroll
    for (int u = 0; u < 8; ++u) {
        A0[u] = PP[2*u] + PP[2*u+1];
        A2[u] = PM[2*u] + PM[2*u+1];
        A1[u] = MP[2*u] + MP[2*u+1];
        A5[u] = MP[2*u] - MP[2*u+1];
    }
    float B0[4], B2[4], B10[4], B1[4], B5[4];
#pragma unroll
    for (int w = 0; w < 4; ++w) {
        B0[w]  = A0[2*w] + A0[2*w+1];
        B2[w]  = A2[2*w] + A2[2*w+1];
        B10[w] = A2[2*w] - A2[2*w+1];
        B1[w]  = A1[2*w] + A1[2*w+1];
        B5[w]  = A5[2*w] + A5[2*w+1];
    }
    float C0[2], C2[2], C10[2], C1[2], C5[2], C21[2];
#pragma unroll
    for (int r = 0; r < 2; ++r) {
        C0[r]  = B0[2*r]  + B0[2*r+1];
        C2[r]  = B2[2*r]  + B2[2*r+1];
        C10[r] = B10[2*r] + B10[2*r+1];
        C1[r]  = B1[2*r]  + B1[2*r+1];
        C5[r]  = B5[2*r]  + B5[2*r+1];
        C21[r] = B5[2*r]  - B5[2*r+1];
    }
    const float T0  = C0[0] + C0[1];
    const float T2  = C2[0] + C2[1];
    const float T10 = C10[0] + C10[1];
    const float T42 = C10[0] - C10[1];
    const float T1  = C1[0] + C1[1];
    const float T5  = C5[0] + C5[1];
    const float T21 = C21[0] + C21[1];

    // ---- lane signs (R_w lane part: wire0->bit0 (odd w? no: R_w with 0) ) ----
    // R0={0}:s1 R1={1}:s2 R2={2,0}:s1*T1 R3={3,1}:s2*T2 R4={4,2,0}:s1*T5
    // R5={5,3,1}:s2*T10 R6={6,4,2,0}:s1*T21 R7={7,5,3,1}:s2*T42
    const float s1 = (ll & 1) ? -1.f : 1.f;
    const float s2 = (ll & 2) ? -1.f : 1.f;
    float z[8] = { s1*T0, s2*T0, s1*T1, s2*T2, s1*T5, s2*T10, s1*T21, s2*T42 };

    // reduce over the 4-lane quad (DPP)
#pragma unroll
    for (int i = 0; i < 8; ++i) {
        float w = z[i];
        w += lx<1>(w);
        w += lx<2>(w);
        z[i] = w;
    }

    if (ll == 0) {
        float4* o = reinterpret_cast<float4*>(out + (size_t)sample * NQ);
        o[0] = make_float4(z[0], z[1], z[2], z[3]);
        o[1] = make_float4(z[4], z[5], z[6], z[7]);
    }
}

extern "C" void kernel_launch(void* const* d_in, const int* in_sizes, int n_in,
                              void* d_out, int out_size, void* d_ws, size_t ws_size,
                              hipStream_t stream) {
    const float* inputs  = (const float*)d_in[0];
    const float* weights = (const float*)d_in[1];
    float* out = (float*)d_out;
    const int B = in_sizes[0] / NQ;               // 65536
    const int total = B * 4;                      // 4 lanes per sample
    const int blocks = (total + 255) / 256;       // 1024
    vqc_kernel<<<blocks, 256, 0, stream>>>(inputs, weights, out, B);
}

// Round 5
// 9.784 us; speedup vs baseline: 10.9100x; 2.8969x over previous
//
#include <hip/hip_runtime.h>

// VQC 8 qubits, closed form via Pauli (Heisenberg) propagation.
//
// Verified frame (rounds 3/4 passed on it): circuit = product of 16 commuting
// X-string rotations applied to the RY product state, with masks
//   layer0 gate w: {w,w+1} (w<7), {7} for w=7       angle alpha_w = weights[0][w]
//   layer1 gate w: {w,w+2} (w<6), {6},{7} for w=6,7 angle beta_w  = weights[1][w]
// and <Z_i> measured with sign row R_i = {i, i-2, i-4, ...}.
//
// Propagating Z^{R_i} through all gates (they mutually commute):
//   <Z_i> = sum over even subsets T of G_i with M_T ∩ R_i = ∅ of
//           (-1)^{|T|/2} prod_T sin(theta) prod_{G_i\T} cos(theta)
//           * prod_{w in M_T} sin(x_w) * prod_{w in R_i} cos(x_w)
// G_i = gates g with |m_g ∩ R_i| odd. Gates group by their unique R-site;
// T picks an even number per site -> nested factored sums below (90 terms).

constexpr int NQ = 8;

__global__ __launch_bounds__(256) void vqc_closed(
    const float* __restrict__ inputs,   // (B, 8) f32
    const float* __restrict__ weights,  // (2, 8) f32
    float* __restrict__ out,            // (B, 8) f32
    int B)
{
    const int t = blockIdx.x * 256 + threadIdx.x;
    if (t >= B) return;

    // ---- per-sample trig (FULL angles) ----
    const float4 a4 = ((const float4*)(inputs + (size_t)t * NQ))[0];
    const float4 b4 = ((const float4*)(inputs + (size_t)t * NQ))[1];
    const float xx[8] = {a4.x, a4.y, a4.z, a4.w, b4.x, b4.y, b4.z, b4.w};
    float sx[8], cx[8];
#pragma unroll
    for (int w = 0; w < 8; ++w) __sincosf(xx[w], &sx[w], &cx[w]);

    // ---- weight trig (FULL angles; uniform across threads) ----
    float sA[8], cA[8], sB[8], cB[8];
#pragma unroll
    for (int w = 0; w < 8; ++w) __sincosf(weights[w], &sA[w], &cA[w]);
#pragma unroll
    for (int w = 0; w < 8; ++w) __sincosf(weights[8 + w], &sB[w], &cB[w]);

    // shared pair products
    const float pA01 = cA[0]*cA[1], qA01 = sA[0]*sA[1];
    const float pA23 = cA[2]*cA[3], qA23 = sA[2]*sA[3];
    const float pA45 = cA[4]*cA[5], qA45 = sA[4]*sA[5];
    const float pA12 = cA[1]*cA[2], qA12 = sA[1]*sA[2];
    const float pA34 = cA[3]*cA[4], qA34 = sA[3]*sA[4];
    // site-7 group of Z7 collapses: E7 (mask {}), O7 (mask {6})
    const float E7 = cA[6]*(cA[7]*cB[7] - sA[7]*sB[7]);   //  cA6*cos(a7+b7)
    const float O7 = -sA[6]*(sA[7]*cB[7] + cA[7]*sB[7]);  // -sA6*sin(a7+b7)

    // ---- closed forms ----
    const float z0 = cx[0]*(cA[0]*cB[0] - sA[0]*sB[0]*sx[1]*sx[2]);

    const float z1 = cx[1]*( cA[0]*cA[1]*cB[1]
                   - sA[0]*sA[1]*cB[1]*sx[0]*sx[2]
                   - sA[0]*cA[1]*sB[1]*sx[0]*sx[3]
                   - cA[0]*sA[1]*sB[1]*sx[2]*sx[3] );

    const float z2 = cx[0]*cx[2]*cA[0]*( cA[1]*cA[2]*cB[2]
                   - sA[1]*sA[2]*cB[2]*sx[1]*sx[3]
                   - sA[1]*cA[2]*sB[2]*sx[1]*sx[4]
                   - cA[1]*sA[2]*sB[2]*sx[3]*sx[4] );

    const float z3 = cx[1]*cx[3]*(
          pA01*( cA[2]*cA[3]*cB[3]
               - sA[2]*sA[3]*cB[3]*sx[2]*sx[4]
               - sA[2]*cA[3]*sB[3]*sx[2]*sx[5]
               - cA[2]*sA[3]*sB[3]*sx[4]*sx[5] )
        - qA01*( cA[2]*cA[3]*cB[3]*sx[0]*sx[2]
               - sA[2]*sA[3]*cB[3]*sx[0]*sx[4]
               - sA[2]*cA[3]*sB[3]*sx[0]*sx[5]
               - cA[2]*sA[3]*sB[3]*sx[0]*sx[2]*sx[4]*sx[5] ) );

    const float z4 = cx[0]*cx[2]*cx[4]*cA[0]*(
          pA12*( cA[3]*cA[4]*cB[4]
               - sA[3]*sA[4]*cB[4]*sx[3]*sx[5]
               - sA[3]*cA[4]*sB[4]*sx[3]*sx[6]
               - cA[3]*sA[4]*sB[4]*sx[5]*sx[6] )
        - qA12*( cA[3]*cA[4]*cB[4]*sx[1]*sx[3]
               - sA[3]*sA[4]*cB[4]*sx[1]*sx[5]
               - sA[3]*cA[4]*sB[4]*sx[1]*sx[6]
               - cA[3]*sA[4]*sB[4]*sx[1]*sx[3]*sx[5]*sx[6] ) );

    const float z5 = cx[1]*cx[3]*cx[5]*(
          pA01*( pA23*( cA[4]*cA[5]*cB[5]
                      - sA[4]*sA[5]*cB[5]*sx[4]*sx[6]
                      - sA[4]*cA[5]*sB[5]*sx[4]*sx[7]
                      - cA[4]*sA[5]*sB[5]*sx[6]*sx[7] )
              - qA23*( cA[4]*cA[5]*cB[5]*sx[2]*sx[4]
                      - sA[4]*sA[5]*cB[5]*sx[2]*sx[6]
                      - sA[4]*cA[5]*sB[5]*sx[2]*sx[7]
                      - cA[4]*sA[5]*sB[5]*sx[2]*sx[4]*sx[6]*sx[7] ) )
        - qA01*( pA23*( cA[4]*cA[5]*cB[5]*sx[0]*sx[2]
                      - sA[4]*sA[5]*cB[5]*sx[0]*sx[2]*sx[4]*sx[6]
                      - sA[4]*cA[5]*sB[5]*sx[0]*sx[2]*sx[4]*sx[7]
                      - cA[4]*sA[5]*sB[5]*sx[0]*sx[2]*sx[6]*sx[7] )
              - qA23*( cA[4]*cA[5]*cB[5]*sx[0]*sx[4]
                      - sA[4]*sA[5]*cB[5]*sx[0]*sx[6]
                      - sA[4]*cA[5]*sB[5]*sx[0]*sx[7]
                      - cA[4]*sA[5]*sB[5]*sx[0]*sx[4]*sx[6]*sx[7] ) ) );

    const float z6 = cx[0]*cx[2]*cx[4]*cx[6]*cA[0]*(
          pA12*( pA34*( cA[5]*cA[6]*cB[6]
                      - sA[5]*sA[6]*cB[6]*sx[5]*sx[7]
                      - sA[5]*cA[6]*sB[6]*sx[5]
                      - cA[5]*sA[6]*sB[6]*sx[7] )
              - qA34*( cA[5]*cA[6]*cB[6]*sx[3]*sx[5]
                      - sA[5]*sA[6]*cB[6]*sx[3]*sx[7]
                      - sA[5]*cA[6]*sB[6]*sx[3]
                      - cA[5]*sA[6]*sB[6]*sx[3]*sx[5]*sx[7] ) )
        - qA12*( pA34*( cA[5]*cA[6]*cB[6]*sx[1]*sx[3]
                      - sA[5]*sA[6]*cB[6]*sx[1]*sx[3]*sx[5]*sx[7]
                      - sA[5]*cA[6]*sB[6]*sx[1]*sx[3]*sx[5]
                      - cA[5]*sA[6]*sB[6]*sx[1]*sx[3]*sx[7] )
              - qA34*( cA[5]*cA[6]*cB[6]*sx[1]*sx[5]
                      - sA[5]*sA[6]*cB[6]*sx[1]*sx[7]
                      - sA[5]*cA[6]*sB[6]*sx[1]
                      - cA[5]*sA[6]*sB[6]*sx[1]*sx[5]*sx[7] ) ) );

    const float z7 = cx[1]*cx[3]*cx[5]*cx[7]*(
          pA01*( pA23*( pA45*( E7 + O7*sx[6] )
                      - qA45*( E7*sx[4]*sx[6] + O7*sx[4] ) )
              - qA23*( pA45*( E7*sx[2]*sx[4] + O7*sx[2]*sx[4]*sx[6] )
                      - qA45*( E7*sx[2]*sx[6] + O7*sx[2] ) ) )
        - qA01*( pA23*( pA45*( E7*sx[0]*sx[2] + O7*sx[0]*sx[2]*sx[6] )
                      - qA45*( E7*sx[0]*sx[2]*sx[4]*sx[6] + O7*sx[0]*sx[2]*sx[4] ) )
              - qA23*( pA45*( E7*sx[0]*sx[4] + O7*sx[0]*sx[4]*sx[6] )
                      - qA45*( E7*sx[0]*sx[6] + O7*sx[0] ) ) ) );

    float4* o = (float4*)(out + (size_t)t * NQ);
    o[0] = make_float4(z0, z1, z2, z3);
    o[1] = make_float4(z4, z5, z6, z7);
}

extern "C" void kernel_launch(void* const* d_in, const int* in_sizes, int n_in,
                              void* d_out, int out_size, void* d_ws, size_t ws_size,
                              hipStream_t stream) {
    const float* inputs  = (const float*)d_in[0];
    const float* weights = (const float*)d_in[1];
    float* out = (float*)d_out;
    const int B = in_sizes[0] / NQ;          // 65536
    const int blocks = (B + 255) / 256;      // 256
    vqc_closed<<<blocks, 256, 0, stream>>>(inputs, weights, out, B);
}